// Round 5
// baseline (357.057 us; speedup 1.0000x reference)
//
#include <hip/hip_runtime.h>
#include <hip/hip_bf16.h>
#include <cstdint>
#include <cstddef>

// B=4, LQ=LK=1024, D=512, H=8. fp32 in/out; bf16 MFMA compute.
// R5: reassociate (P.V).Wp^T = P.(V.Wp^T); fuse ctx+outproj+normalization into
// one K=2048 GEMM with per-h sinv rescale; rowsum folded into scores epilogue
// (atomics); rowsum/ctx/outproj dispatches deleted.

typedef __bf16 bf16;
typedef __bf16 bf16x4 __attribute__((ext_vector_type(4)));
typedef __bf16 bf16x8 __attribute__((ext_vector_type(8)));
typedef float f32x4 __attribute__((ext_vector_type(4)));

__device__ inline void gload_lds16(const void* g, void* l) {
  __builtin_amdgcn_global_load_lds(
      (const __attribute__((address_space(1))) void*)g,
      (__attribute__((address_space(3))) void*)l, 16, 0, 0);
}

// Convert six fp32 tensors (2M elements each) to bf16. grid: (2048, 6).
__global__ __launch_bounds__(256) void cvt6(
    const float* __restrict__ s0, const float* __restrict__ s1,
    const float* __restrict__ s2, const float* __restrict__ s3,
    const float* __restrict__ s4, const float* __restrict__ s5,
    bf16* __restrict__ d0, bf16* __restrict__ d1, bf16* __restrict__ d2,
    bf16* __restrict__ d3, bf16* __restrict__ d4, bf16* __restrict__ d5)
{
  const float* s; bf16* d;
  switch (blockIdx.y) {
    case 0: s = s0; d = d0; break;
    case 1: s = s1; d = d1; break;
    case 2: s = s2; d = d2; break;
    case 3: s = s3; d = d3; break;
    case 4: s = s4; d = d4; break;
    default: s = s5; d = d5; break;
  }
  const int i = (blockIdx.x * 256 + threadIdx.x) * 4;
  float4 v = *(const float4*)(s + i);
  bf16x4 o;
  o[0] = (bf16)v.x; o[1] = (bf16)v.y; o[2] = (bf16)v.z; o[3] = (bf16)v.w;
  *(bf16x4*)(d + i) = o;
}

// Tile body: C[128,128] at (m0,n0) of scale*(A . B^T). BK=64, 256 thr.
// LDS swizzle: global 16B-chunk c of row r lives at slot c ^ (r&7).
// MODE 0: C = acc*scale.
// MODE 1: P = mask ? exp(acc*scale) : 0 -> C (bf16); atomicAdd row-sums.
template <typename CT, int MODE>
__device__ __forceinline__ void gemm_body(
    bf16* As, bf16* Bs,
    const bf16* __restrict__ A, const bf16* __restrict__ B, CT* __restrict__ C,
    int K, int lda, int ldb, int ldc, int m0, int n0, float scale,
    const int* __restrict__ mrow, float* __restrict__ sumrow)
{
  const int t = threadIdx.x;
  const int lane = t & 63, w = t >> 6;
  const int wm = w >> 1, wn = w & 1;

  const int srow = t >> 3;                       // 0..31
  const int schunk = (t & 7) ^ (srow & 7);       // swizzled source chunk
  const bf16* Ag = A + (size_t)(m0 + srow) * lda + schunk * 8;
  const bf16* Bg = B + (size_t)(n0 + srow) * ldb + schunk * 8;
  bf16* Als = As + t * 8;
  bf16* Bls = Bs + t * 8;

  f32x4 acc[4][4] = {};
  const int rr = lane & 15;
  const int q4 = lane >> 4;

  const int kIters = K >> 6;
  for (int kt = 0; kt < kIters; ++kt) {
    __syncthreads();
#pragma unroll
    for (int i = 0; i < 4; ++i) {
      gload_lds16(Ag + (size_t)(32 * i) * lda, Als + i * 2048);
      gload_lds16(Bg + (size_t)(32 * i) * ldb, Bls + i * 2048);
    }
    Ag += 64; Bg += 64;
    __syncthreads();

#pragma unroll
    for (int kk = 0; kk < 2; ++kk) {
      bf16x8 af[4], bfr[4];
      const int ck = kk * 4 + q4;
#pragma unroll
      for (int r = 0; r < 4; ++r) {
        const int R = wm * 64 + r * 16 + rr;
        af[r] = *(const bf16x8*)(As + R * 64 + ((ck ^ (R & 7)) << 3));
      }
#pragma unroll
      for (int c = 0; c < 4; ++c) {
        const int R = wn * 64 + c * 16 + rr;
        bfr[c] = *(const bf16x8*)(Bs + R * 64 + ((ck ^ (R & 7)) << 3));
      }
#pragma unroll
      for (int r = 0; r < 4; ++r)
#pragma unroll
        for (int c = 0; c < 4; ++c)
          acc[r][c] = __builtin_amdgcn_mfma_f32_16x16x32_bf16(af[r], bfr[c], acc[r][c], 0, 0, 0);
    }
  }

  // C/D frag: col = lane&15, row = (lane>>4)*4 + reg
  const int cr0 = q4 << 2;
#pragma unroll
  for (int r = 0; r < 4; ++r) {
#pragma unroll
    for (int c = 0; c < 4; ++c) {
      const int gr0 = m0 + wm * 64 + r * 16 + cr0;
      const int gc = n0 + wn * 64 + c * 16 + rr;
#pragma unroll
      for (int i = 0; i < 4; ++i) {
        const int gr = gr0 + i;
        float v = acc[r][c][i];
        if (MODE == 0) {
          C[(size_t)gr * ldc + gc] = (CT)(v * scale);
        } else {
          const int m = mrow[((size_t)gr << 10) + gc];
          float pv = m ? __expf(v * scale) : 0.0f;
          C[(size_t)gr * ldc + gc] = (CT)pv;
          acc[r][c][i] = pv;   // keep for rowsum
        }
      }
    }
  }
  if (MODE == 1) {
    // row partial sums over this block's 64 cols per wave; xor-reduce over rr.
#pragma unroll
    for (int r = 0; r < 4; ++r) {
#pragma unroll
      for (int i = 0; i < 4; ++i) {
        float s = (acc[r][0][i] + acc[r][1][i]) + (acc[r][2][i] + acc[r][3][i]);
        s += __shfl_xor(s, 1); s += __shfl_xor(s, 2);
        s += __shfl_xor(s, 4); s += __shfl_xor(s, 8);
        if (rr == 0)
          atomicAdd(sumrow + (m0 + wm * 64 + r * 16 + cr0 + i), s);
      }
    }
  }
}

// Generic batched NT GEMM: z = b*8+h with per-operand b/h strides.
template <typename CT, int MODE>
__global__ __launch_bounds__(256) void gemm_nt(
    const bf16* __restrict__ A, const bf16* __restrict__ B, CT* __restrict__ C,
    int K, int lda, int ldb, int ldc,
    long ab, long ah, long bbs, long bh, long cb, long ch, float scale,
    const int* __restrict__ mask, float* __restrict__ sums)
{
  __shared__ bf16 As[128 * 64];
  __shared__ bf16 Bs[128 * 64];
  const int z = blockIdx.z;
  const int zb = z >> 3, zh = z & 7;
  A += (size_t)zb * ab + (size_t)zh * ah;
  B += (size_t)zb * bbs + (size_t)zh * bh;
  C += (size_t)zb * cb + (size_t)zh * ch;
  const int* mrow = (MODE == 1) ? mask + ((size_t)zb << 20) : nullptr;
  float* sumrow = (MODE == 1) ? sums + ((size_t)z << 10) : nullptr;
  gemm_body<CT, MODE>(As, Bs, A, B, C, K, lda, ldb, ldc,
                      blockIdx.y * 128, blockIdx.x * 128, scale, mrow, sumrow);
}

// Fused q/k/v projections (all M=1024,N=512,K=512). grid (32, 32, 3).
__global__ __launch_bounds__(256) void qkv_kernel(
    const bf16* __restrict__ xb, const bf16* __restrict__ stb,
    const bf16* __restrict__ wqb, const bf16* __restrict__ wkb,
    const bf16* __restrict__ wvb,
    bf16* __restrict__ q, bf16* __restrict__ k, bf16* __restrict__ v)
{
  __shared__ bf16 As[128 * 64];
  __shared__ bf16 Bs[128 * 64];
  const int tile = blockIdx.x;
  const int zz = blockIdx.y;
  const int job = blockIdx.z;
  const size_t zb = zz >> 3, zh = zz & 7;
  const bf16* Ain = (job == 0) ? xb : stb;
  const bf16* W = (job == 0) ? wqb : (job == 1) ? wkb : wvb;
  bf16* Cout = (job == 0) ? q : (job == 1) ? k : v;
  gemm_body<bf16, 0>(As, Bs, Ain + zb * 524288, W + zh * 262144,
      Cout + zb * 4194304 + zh * 524288, 512, 512, 512, 512,
      (tile >> 2) * 128, (tile & 3) * 128, 1.0f, nullptr, nullptr);
}

// out_part[hp] = sum_{h in pair} sinv_h ⊙ (P_h · VWT_h^T).
// grid (4 e-tiles, 8 l-tiles, 16 = b*4+hp). fp32 out.
__global__ __launch_bounds__(256) void pvw_kernel(
    const bf16* __restrict__ P, const bf16* __restrict__ VWT,
    const float* __restrict__ sums, float* __restrict__ part)
{
  __shared__ bf16 As[128 * 64];
  __shared__ bf16 Bs[128 * 64];
  const int z = blockIdx.z;
  const int zb = z >> 2, hp = z & 3;
  const int m0 = blockIdx.y * 128, n0 = blockIdx.x * 128;
  const int t = threadIdx.x;
  const int lane = t & 63, w = t >> 6;
  const int wm = w >> 1, wn = w & 1;
  const int srow = t >> 3, schunk = (t & 7) ^ (srow & 7);
  const int rr = lane & 15, q4 = lane >> 4;
  bf16* Als = As + t * 8;
  bf16* Bls = Bs + t * 8;

  f32x4 accO[4][4] = {};

#pragma unroll
  for (int hh = 0; hh < 2; ++hh) {
    const int h = hp * 2 + hh;
    const bf16* Ag = P + (size_t)zb * 8388608 + (size_t)h * 1048576
                       + (size_t)(m0 + srow) * 1024 + schunk * 8;
    const bf16* Bg = VWT + (size_t)zb * 4194304 + (size_t)h * 524288
                        + (size_t)(n0 + srow) * 1024 + schunk * 8;
    f32x4 acc[4][4] = {};
    for (int kt = 0; kt < 16; ++kt) {
      __syncthreads();
#pragma unroll
      for (int i = 0; i < 4; ++i) {
        gload_lds16(Ag + (size_t)(32 * i) * 1024, Als + i * 2048);
        gload_lds16(Bg + (size_t)(32 * i) * 1024, Bls + i * 2048);
      }
      Ag += 64; Bg += 64;
      __syncthreads();
#pragma unroll
      for (int kk = 0; kk < 2; ++kk) {
        bf16x8 af[4], bfr[4];
        const int ck = kk * 4 + q4;
#pragma unroll
        for (int r = 0; r < 4; ++r) {
          const int R = wm * 64 + r * 16 + rr;
          af[r] = *(const bf16x8*)(As + R * 64 + ((ck ^ (R & 7)) << 3));
        }
#pragma unroll
        for (int c = 0; c < 4; ++c) {
          const int R = wn * 64 + c * 16 + rr;
          bfr[c] = *(const bf16x8*)(Bs + R * 64 + ((ck ^ (R & 7)) << 3));
        }
#pragma unroll
        for (int r = 0; r < 4; ++r)
#pragma unroll
          for (int c = 0; c < 4; ++c)
            acc[r][c] = __builtin_amdgcn_mfma_f32_16x16x32_bf16(af[r], bfr[c], acc[r][c], 0, 0, 0);
      }
    }
    // per-h normalization, accumulate into output accumulator
    const float* srs = sums + ((size_t)zb * 8 + h) * 1024;
#pragma unroll
    for (int r = 0; r < 4; ++r) {
#pragma unroll
      for (int i = 0; i < 4; ++i) {
        const float inv = 1.0f / srs[m0 + wm * 64 + r * 16 + (q4 << 2) + i];
#pragma unroll
        for (int c = 0; c < 4; ++c)
          accO[r][c][i] += acc[r][c][i] * inv;
      }
    }
  }

  float* Cp = part + (size_t)hp * 2097152 + (size_t)zb * 524288;
#pragma unroll
  for (int r = 0; r < 4; ++r) {
#pragma unroll
    for (int c = 0; c < 4; ++c) {
      const int gr0 = m0 + wm * 64 + r * 16 + (q4 << 2);
      const int gc = n0 + wn * 64 + c * 16 + rr;
#pragma unroll
      for (int i = 0; i < 4; ++i)
        Cp[(size_t)(gr0 + i) * 512 + gc] = accO[r][c][i];
    }
  }
}

// out = part0+part1+part2+part3 (fp32, 2M elems). grid 2048 x 256.
__global__ __launch_bounds__(256) void reduce4(
    const float* __restrict__ part, float* __restrict__ out)
{
  const size_t i = ((size_t)blockIdx.x * 256 + threadIdx.x) * 4;
  float4 a = *(const float4*)(part + i);
  float4 b = *(const float4*)(part + 2097152 + i);
  float4 c = *(const float4*)(part + 4194304 + i);
  float4 d = *(const float4*)(part + 6291456 + i);
  float4 o;
  o.x = (a.x + b.x) + (c.x + d.x);
  o.y = (a.y + b.y) + (c.y + d.y);
  o.z = (a.z + b.z) + (c.z + d.z);
  o.w = (a.w + b.w) + (c.w + d.w);
  *(float4*)(out + i) = o;
}

extern "C" void kernel_launch(void* const* d_in, const int* in_sizes, int n_in,
                              void* d_out, int out_size, void* d_ws, size_t ws_size,
                              hipStream_t stream) {
  const float* x    = (const float*)d_in[0];
  const float* st   = (const float*)d_in[1];
  const int*   mask = (const int*)d_in[2];
  const float* Wq   = (const float*)d_in[3];
  const float* Wk   = (const float*)d_in[4];
  const float* Wv   = (const float*)d_in[5];
  const float* Wp   = (const float*)d_in[6];
  float* out = (float*)d_out;

  char* ws = (char*)d_ws;
  const size_t MB = 1048576;
  bf16* xb  = (bf16*)(ws);              // 4MB; dead after qkv -> sums overlays
  bf16* stb = (bf16*)(ws + 4 * MB);
  bf16* wqb = (bf16*)(ws + 8 * MB);
  bf16* wkb = (bf16*)(ws + 12 * MB);
  bf16* wvb = (bf16*)(ws + 16 * MB);
  bf16* wpb = (bf16*)(ws + 20 * MB);
  bf16*  q   = (bf16*)(ws + 24 * MB);   // 32MB; dead after scores -> VWT overlays
  bf16*  k   = (bf16*)(ws + 56 * MB);   // 32MB; dead after scores -> part overlays
  bf16*  v   = (bf16*)(ws + 88 * MB);   // 32MB [4,8,1024,512]
  bf16*  sc  = (bf16*)(ws + 120 * MB);  // 64MB P = exp(scores) [4,8,1024,1024]
  bf16*  VWT = (bf16*)(ws + 24 * MB);   // 32MB [4,8,512,1024]
  float* sums = (float*)(ws);           // 128KB [32,1024]
  float* part = (float*)(ws + 56 * MB); // 32MB [4][4,1024,512] fp32

  dim3 blk(256);
  const float scale = 0.04419417382415922f;  // 1/sqrt(512)

  cvt6<<<dim3(2048, 6), blk, 0, stream>>>(x, st, Wq, Wk, Wv, Wp,
                                          xb, stb, wqb, wkb, wvb, wpb);

  // q/k/v projections (3072 blocks)
  qkv_kernel<<<dim3(32, 32, 3), blk, 0, stream>>>(xb, stb, wqb, wkb, wvb, q, k, v);

  // zero row-sum accumulators (xb region is dead now)
  hipMemsetAsync(sums, 0, 32 * 1024 * sizeof(float), stream);

  // P = mask ? exp(scale * q.k^T) : 0; rowsums via atomics. (M=N=1024, K=512)
  gemm_nt<bf16, 1><<<dim3(8, 8, 32), blk, 0, stream>>>(q, k, sc, 512, 512, 512, 1024,
      4194304L, 524288L, 4194304L, 524288L, 8388608L, 1048576L, scale, mask, sums);

  // VWT[b,h][e,s] = Wp_h . v[b,h]^T  (M=512, N=1024, K=512) -> overlays q
  gemm_nt<bf16, 0><<<dim3(8, 4, 32), blk, 0, stream>>>(wpb, v, VWT, 512, 4096, 512, 1024,
      0L, 512L, 4194304L, 524288L, 4194304L, 524288L, 1.0f, nullptr, nullptr);

  // out partials: sum over h-pairs of sinv ⊙ (P_h . VWT_h^T)
  pvw_kernel<<<dim3(4, 8, 16), blk, 0, stream>>>(sc, VWT, sums, part);

  // out = sum of 4 partials
  reduce4<<<dim3(2048), blk, 0, stream>>>(part, out);
}